// Round 8
// baseline (1836.634 us; speedup 1.0000x reference)
//
#include <hip/hip_runtime.h>
#include <cstdint>
#include <cstddef>

#define VN 100000
#define EN 1600000
static constexpr float BN_EPS_F = 1e-5f;
static constexpr float INV_N = 1.0f / 400000.0f;   // B*V = 4*100000

using short8 = __attribute__((ext_vector_type(8))) short;
using f32x4  = __attribute__((ext_vector_type(4))) float;

// ---------- bf16 helpers (manual, RTNE) ----------
__device__ __forceinline__ float bf_lo(unsigned int p) {
  return __builtin_bit_cast(float, p << 16);
}
__device__ __forceinline__ float bf_hi(unsigned int p) {
  return __builtin_bit_cast(float, p & 0xffff0000u);
}
__device__ __forceinline__ float bf1(unsigned short u) {
  return __builtin_bit_cast(float, ((unsigned int)u) << 16);
}
__device__ __forceinline__ unsigned short f2bf(float f) {
  unsigned int x = __builtin_bit_cast(unsigned int, f);
  x += 0x7fffu + ((x >> 16) & 1u);
  return (unsigned short)(x >> 16);
}
__device__ __forceinline__ unsigned int pack2(float a, float b) {
  return (unsigned int)f2bf(a) | ((unsigned int)f2bf(b) << 16);
}

// ---------- K1: per-channel sum/sumsq of input x (B,32,V) fp32 ----------
__global__ __launch_bounds__(256) void stats_x_kernel(const float* __restrict__ x,
                                                      float* __restrict__ stats) {
  const int p = blockIdx.x & 127;      // plane = (b,c)
  const int chunk = blockIdx.x >> 7;   // 0..7
  const int c = p & 31, b = p >> 5;
  const float* base = x + ((size_t)b * 32 + c) * VN + chunk * 12500;
  float s = 0.f, s2 = 0.f;
  for (int i = threadIdx.x; i < 12500; i += 256) {
    float v = base[i];
    s += v; s2 += v * v;
  }
  __shared__ float r1[256], r2[256];
  r1[threadIdx.x] = s; r2[threadIdx.x] = s2;
  __syncthreads();
  for (int off = 128; off > 0; off >>= 1) {
    if (threadIdx.x < off) {
      r1[threadIdx.x] += r1[threadIdx.x + off];
      r2[threadIdx.x] += r2[threadIdx.x + off];
    }
    __syncthreads();
  }
  if (threadIdx.x == 0) {
    atomicAdd(&stats[c], r1[0]);
    atomicAdd(&stats[64 + c], r2[0]);
  }
}

__global__ void finalize_stats_kernel(float* __restrict__ stats,
                                      const float* __restrict__ g,
                                      const float* __restrict__ beta, int C) {
  int c = threadIdx.x;
  if (c < C) {
    float m = stats[c] * INV_N;
    float var = stats[64 + c] * INV_N - m * m;
    float sc = g[c] * rsqrtf(var + BN_EPS_F);
    stats[128 + c] = sc;
    stats[192 + c] = beta[c] - m * sc;
  }
}

// ---------- K2: normalize input + transpose (B,32,V)->(V, B=4, C=32) bf16, stride 128 ----------
__global__ __launch_bounds__(128) void bn_transpose_kernel(const float* __restrict__ x,
                                                           const float* __restrict__ stats,
                                                           unsigned short* __restrict__ xn) {
  const int tid = threadIdx.x;       // tid = b*32 + c
  const int b = tid >> 5, c = tid & 31;
  const int v0 = blockIdx.x * 64;
  const float sc = stats[128 + c], sh = stats[192 + c];
  const float* src = x + ((size_t)b * 32 + c) * VN;
  for (int i = 0; i < 64; i++) {
    int v = v0 + i;
    if (v < VN) xn[(size_t)v * 128 + tid] = f2bf(sc * src[v] + sh);
  }
}

// ---------- W pre-pack: fp32 (K,Cin,Cout) -> bf16 MFMA B-fragment order ----------
// Layout [k][kc][t][lane][j]: value = W[k][c = kc*32 + (lane>>4)*8 + j][o = t*16 + (lane&15)]
__global__ __launch_bounds__(256) void pack_wb_kernel(const float* __restrict__ W,
                                                      unsigned short* __restrict__ Wb,
                                                      int Cin, int Cout) {
  const int i = blockIdx.x * 256 + threadIdx.x;
  const int KC = Cin >> 5, T = Cout >> 4;
  const int tot = 4 * KC * T * 512;
  if (i >= tot) return;
  const int j = i & 7;
  const int l = (i >> 3) & 63;
  const int rem = i >> 9;
  const int t = rem % T;
  const int kc = (rem / T) % KC;
  const int k = rem / (T * KC);
  const int c = kc * 32 + (l >> 4) * 8 + j;
  const int o = t * 16 + (l & 15);
  Wb[i] = f2bf(W[((size_t)k * Cin + c) * Cout + o]);
}

// ---------- CSR build ----------
__global__ __launch_bounds__(256) void hist_kernel(const int* __restrict__ rows,
                                                   int* __restrict__ cnt) {
  int i = blockIdx.x * blockDim.x + threadIdx.x;
  const int stride = gridDim.x * blockDim.x;
  for (; i < EN; i += stride) atomicAdd(&cnt[rows[i]], 1);
}

__global__ __launch_bounds__(256) void scan1_kernel(const int* __restrict__ cnt,
                                                    int* __restrict__ rp,
                                                    int* __restrict__ chunkSums) {
  __shared__ int sh[256];
  const int t = threadIdx.x;
  const int base = blockIdx.x * 2048 + t * 8;
  int vals[8]; int tot = 0;
#pragma unroll
  for (int i = 0; i < 8; i++) {
    int idx = base + i;
    int v = (idx < VN) ? cnt[idx] : 0;
    vals[i] = v; tot += v;
  }
  sh[t] = tot;
  __syncthreads();
  for (int off = 1; off < 256; off <<= 1) {
    int v = (t >= off) ? sh[t - off] : 0;
    __syncthreads();
    sh[t] += v;
    __syncthreads();
  }
  int run = sh[t] - tot;
#pragma unroll
  for (int i = 0; i < 8; i++) {
    int idx = base + i;
    if (idx < VN) rp[idx] = run;
    run += vals[i];
  }
  if (t == 255) chunkSums[blockIdx.x] = sh[255];
}

__global__ void scan2_kernel(const int* __restrict__ chunkSums,
                             int* __restrict__ chunkOff,
                             int* __restrict__ rp, int nChunks) {
  if (threadIdx.x == 0 && blockIdx.x == 0) {
    int off = 0;
    for (int j = 0; j < nChunks; j++) { chunkOff[j] = off; off += chunkSums[j]; }
    rp[VN] = off;
  }
}

__global__ __launch_bounds__(256) void scan3_kernel(int* __restrict__ rp,
                                                    const int* __restrict__ chunkOff,
                                                    int* __restrict__ fill) {
  int i = blockIdx.x * 256 + threadIdx.x;
  if (i < VN) {
    int v = rp[i] + chunkOff[i >> 11];
    rp[i] = v;
    fill[i] = v;
  }
}

__global__ __launch_bounds__(256) void fill_kernel(const int* __restrict__ rows,
                                                   const int* __restrict__ cols,
                                                   const float* __restrict__ lap,
                                                   int* __restrict__ fill,
                                                   int* __restrict__ cols_s,
                                                   float* __restrict__ vals_s) {
  int i = blockIdx.x * blockDim.x + threadIdx.x;
  const int stride = gridDim.x * blockDim.x;
  for (; i < EN; i += stride) {
    int r = rows[i];
    int pos = atomicAdd(&fill[r], 1);
    cols_s[pos] = cols[i];
    vals_s[pos] = lap[i];
  }
}

// ---------- SpMM slice: one wave per row, uint (2 elems) per lane, batch-half slice ----------
// soff = slice offset in shorts (0 or 128 for stride-256 (B,C) rows). Splitting a
// C=64 SpMM into two batch-half launches halves the per-launch gather footprint
// (51 -> 25.6 MB) to raise L2 hit; semantics are bit-identical (batches independent).
// Predicated 8-edge unroll -> up to 8 row-slices (4 lines each... 256 B) in flight/wave.
template <bool CHEB>
__global__ __launch_bounds__(256, 8) void spmm_kernel(const int* __restrict__ rp,
                                                      const int* __restrict__ cs,
                                                      const float* __restrict__ vs,
                                                      const unsigned short* __restrict__ X, int XS,
                                                      const unsigned short* __restrict__ P, int PS,
                                                      unsigned short* __restrict__ Y, int YS,
                                                      int soff) {
  const int lane = threadIdx.x & 63;
  const int row = blockIdx.x * 4 + (threadIdx.x >> 6);
  const int start = rp[row], end = rp[row + 1];
  float a0 = 0.f, a1 = 0.f;
  if (start < end) {
    for (int e0 = start; e0 < end; e0 += 8) {
      int c[8]; float w[8];
#pragma unroll
      for (int i = 0; i < 8; i++) {
        const int e = e0 + i;
        const int ee = (e < end) ? e : (end - 1);
        c[i] = cs[ee];
        w[i] = (e < end) ? vs[ee] : 0.f;
      }
      unsigned int q[8];
#pragma unroll
      for (int i = 0; i < 8; i++) {
        q[i] = *reinterpret_cast<const unsigned int*>(X + (size_t)c[i] * XS + soff + lane * 2);
      }
#pragma unroll
      for (int i = 0; i < 8; i++) {
        a0 += w[i] * bf_lo(q[i]);
        a1 += w[i] * bf_hi(q[i]);
      }
    }
  }
  if constexpr (CHEB) {
    const unsigned int p = *reinterpret_cast<const unsigned int*>(P + (size_t)row * PS + soff + lane * 2);
    a0 = 2.f * a0 - bf_lo(p);
    a1 = 2.f * a1 - bf_hi(p);
  }
  *reinterpret_cast<unsigned int*>(Y + (size_t)row * YS + soff + lane * 2) = pack2(a0, a1);
}

// ---------- fused: x3 = 2*L(B) - A (regs->LDS), OUT = sum_k xk Wk + bias via MFMA -> overwrite A ----------
// einsum = per-block GEMM M=16 (4 rows x 4 batch), N=Cout, K=4*Cin via
// v_mfma_f32_16x16x32_bf16. C/D: col=lane&15, row=(lane>>4)*4+reg (m89-verified).
template <int Cin, int Cout, int X0S>
__global__ __launch_bounds__(256, 8) void fused_cheb_kernel(const int* __restrict__ rp,
                                                         const int* __restrict__ cs,
                                                         const float* __restrict__ vs,
                                                         const unsigned short* __restrict__ X0,
                                                         unsigned short* __restrict__ A,
                                                         const unsigned short* __restrict__ B,
                                                         const unsigned short* __restrict__ Wb,
                                                         const float* __restrict__ Bias) {
  constexpr int EPL = Cin * 4 / 64;  // 2 or 4
  constexpr int ROWSH = Cin * 4;     // shorts per row in (B,C) layout
  __shared__ unsigned short t3s[4 * ROWSH];
  const int lane = threadIdx.x & 63;
  const int wv = threadIdx.x >> 6;
  const int row0 = blockIdx.x * 4;
  const int row = row0 + wv;

  // ---- phase 1: g = (L x2)[row] lane chunk (4-edge unroll); t3 = 2g - x1 -> LDS ----
  float g[EPL];
#pragma unroll
  for (int j = 0; j < EPL; j++) g[j] = 0.f;
  const int start = rp[row], end = rp[row + 1];
  int e = start;
  for (; e + 4 <= end; e += 4) {
    const int c0 = cs[e], c1 = cs[e + 1], c2 = cs[e + 2], c3 = cs[e + 3];
    const float w0 = vs[e], w1 = vs[e + 1], w2 = vs[e + 2], w3 = vs[e + 3];
    if constexpr (EPL == 4) {
      const uint2 q0 = *reinterpret_cast<const uint2*>(B + (size_t)c0 * 256 + lane * 4);
      const uint2 q1 = *reinterpret_cast<const uint2*>(B + (size_t)c1 * 256 + lane * 4);
      const uint2 q2 = *reinterpret_cast<const uint2*>(B + (size_t)c2 * 256 + lane * 4);
      const uint2 q3 = *reinterpret_cast<const uint2*>(B + (size_t)c3 * 256 + lane * 4);
      g[0] += w0 * bf_lo(q0.x) + w1 * bf_lo(q1.x) + w2 * bf_lo(q2.x) + w3 * bf_lo(q3.x);
      g[1] += w0 * bf_hi(q0.x) + w1 * bf_hi(q1.x) + w2 * bf_hi(q2.x) + w3 * bf_hi(q3.x);
      g[2] += w0 * bf_lo(q0.y) + w1 * bf_lo(q1.y) + w2 * bf_lo(q2.y) + w3 * bf_lo(q3.y);
      g[3] += w0 * bf_hi(q0.y) + w1 * bf_hi(q1.y) + w2 * bf_hi(q2.y) + w3 * bf_hi(q3.y);
    } else {
      const unsigned int q0 = *reinterpret_cast<const unsigned int*>(B + (size_t)c0 * 256 + lane * 2);
      const unsigned int q1 = *reinterpret_cast<const unsigned int*>(B + (size_t)c1 * 256 + lane * 2);
      const unsigned int q2 = *reinterpret_cast<const unsigned int*>(B + (size_t)c2 * 256 + lane * 2);
      const unsigned int q3 = *reinterpret_cast<const unsigned int*>(B + (size_t)c3 * 256 + lane * 2);
      g[0] += w0 * bf_lo(q0) + w1 * bf_lo(q1) + w2 * bf_lo(q2) + w3 * bf_lo(q3);
      g[1] += w0 * bf_hi(q0) + w1 * bf_hi(q1) + w2 * bf_hi(q2) + w3 * bf_hi(q3);
    }
  }
  for (; e < end; e++) {
    const int c0 = cs[e];
    const float w0 = vs[e];
    if constexpr (EPL == 4) {
      const uint2 q0 = *reinterpret_cast<const uint2*>(B + (size_t)c0 * 256 + lane * 4);
      g[0] += w0 * bf_lo(q0.x);
      g[1] += w0 * bf_hi(q0.x);
      g[2] += w0 * bf_lo(q0.y);
      g[3] += w0 * bf_hi(q0.y);
    } else {
      const unsigned int q0 = *reinterpret_cast<const unsigned int*>(B + (size_t)c0 * 256 + lane * 2);
      g[0] += w0 * bf_lo(q0);
      g[1] += w0 * bf_hi(q0);
    }
  }
  {
    unsigned int* tw = reinterpret_cast<unsigned int*>(t3s + wv * ROWSH);
    if constexpr (EPL == 4) {
      const uint2 p = *reinterpret_cast<const uint2*>(A + (size_t)row * 256 + lane * 4);
      tw[lane * 2]     = pack2(2.f * g[0] - bf_lo(p.x), 2.f * g[1] - bf_hi(p.x));
      tw[lane * 2 + 1] = pack2(2.f * g[2] - bf_lo(p.y), 2.f * g[3] - bf_hi(p.y));
    } else {
      const unsigned int p = *reinterpret_cast<const unsigned int*>(A + (size_t)row * 256 + lane * 2);
      tw[lane] = pack2(2.f * g[0] - bf_lo(p), 2.f * g[1] - bf_hi(p));
    }
  }
  __syncthreads();  // all 4 rows' t3 visible to all waves

  // ---- phase 2: MFMA einsum ----
  constexpr int KC = Cin / 32;   // mfma K-chunks per Chebyshev order
  constexpr int T = Cout / 16;   // o-tiles
  const int col = lane & 15, quad = lane >> 4;
  const int t = wv % T;
  const int ar = col >> 2, ab = col & 3;  // A-operand m -> (row_local, batch)

  const unsigned short* xap[3];
  xap[0] = X0 + (size_t)(row0 + ar) * X0S + ab * Cin + quad * 8;
  xap[1] = A  + (size_t)(row0 + ar) * 256 + ab * Cin + quad * 8;
  xap[2] = B  + (size_t)(row0 + ar) * 256 + ab * Cin + quad * 8;
  const unsigned short* wb = Wb + (size_t)t * 512 + lane * 8;

  f32x4 acc = {0.f, 0.f, 0.f, 0.f};
#pragma unroll
  for (int k = 0; k < 3; k++) {
#pragma unroll
    for (int kc = 0; kc < KC; kc++) {
      const short8 af = *reinterpret_cast<const short8*>(xap[k] + kc * 32);
      const short8 bf = *reinterpret_cast<const short8*>(wb + (size_t)(k * KC + kc) * T * 512);
      acc = __builtin_amdgcn_mfma_f32_16x16x32_bf16(af, bf, acc, 0, 0, 0);
    }
  }
#pragma unroll
  for (int kc = 0; kc < KC; kc++) {  // k = 3 from LDS
    const short8 af = *reinterpret_cast<const short8*>(&t3s[ar * ROWSH + ab * Cin + kc * 32 + quad * 8]);
    const short8 bf = *reinterpret_cast<const short8*>(wb + (size_t)(3 * KC + kc) * T * 512);
    acc = __builtin_amdgcn_mfma_f32_16x16x32_bf16(af, bf, acc, 0, 0, 0);
  }
  __syncthreads();  // drain all waves' A/B-row fragment reads before in-place write

  if (T == 4 || wv < 2) {  // T==2: waves 2,3 are redundant duplicates
    const int og = t * 16 + col;
    const float bs = Bias[og];
#pragma unroll
    for (int r = 0; r < 4; r++) {
      A[(size_t)(row0 + quad) * 256 + r * Cout + og] = f2bf(acc[r] + bs);
    }
  }
}

// ---------- stats of relu(SRC): rows (V)[b][o] stride 256, o in 0..63 ----------
__global__ __launch_bounds__(256) void stats_out_kernel(const unsigned short* __restrict__ SRC,
                                                        float* __restrict__ stats) {
  const int tid = threadIdx.x;  // tid = b*64 + o
  const int per = (VN + gridDim.x - 1) / gridDim.x;
  const int v0 = blockIdx.x * per;
  const int v1 = (v0 + per < VN) ? (v0 + per) : VN;
  float s = 0.f, s2 = 0.f;
  for (int v = v0; v < v1; v++) {
    float val = bf1(SRC[(size_t)v * 256 + tid]);
    val = fmaxf(val, 0.f);
    s += val; s2 += val * val;
  }
  __shared__ float r1[256], r2[256];
  r1[tid] = s; r2[tid] = s2;
  __syncthreads();
  if (tid < 64) {  // sum the 4 batches for channel o = tid
    float a = r1[tid] + r1[tid + 64] + r1[tid + 128] + r1[tid + 192];
    float b = r2[tid] + r2[tid + 64] + r2[tid + 128] + r2[tid + 192];
    atomicAdd(&stats[tid], a);
    atomicAdd(&stats[64 + tid], b);
  }
}

// ---------- relu + BN normalize: SRC -> DST, rows [b][o] stride 256, bf16 ----------
__global__ __launch_bounds__(256) void bn_relu_kernel(const unsigned short* __restrict__ SRC,
                                                      const float* __restrict__ stats,
                                                      unsigned short* __restrict__ DST) {
  const int i = blockIdx.x * 256 + threadIdx.x;  // uint2 index (4 consecutive o, same b)
  const int w = i & 63;
  const int o0 = (w & 15) * 4;
  const float4 sc4 = *reinterpret_cast<const float4*>(stats + 128 + o0);
  const float4 sh4 = *reinterpret_cast<const float4*>(stats + 192 + o0);
  const uint2 q = reinterpret_cast<const uint2*>(SRC)[i];
  float a = fmaxf(bf_lo(q.x), 0.f);
  float b = fmaxf(bf_hi(q.x), 0.f);
  float c = fmaxf(bf_lo(q.y), 0.f);
  float d = fmaxf(bf_hi(q.y), 0.f);
  uint2 r;
  r.x = pack2(a * sc4.x + sh4.x, b * sc4.y + sh4.y);
  r.y = pack2(c * sc4.z + sh4.z, d * sc4.w + sh4.w);
  reinterpret_cast<uint2*>(DST)[i] = r;
}

// ---------- final: out[b,o,v] = relu(SRC[v,b,o] + xn[v,b,o]) ----------
__global__ __launch_bounds__(256) void final_kernel(const unsigned short* __restrict__ SRC,
                                                    const unsigned short* __restrict__ xn,
                                                    float* __restrict__ out) {
  const int lane = threadIdx.x & 63;
  const int grp = threadIdx.x >> 6;  // 0..3
  const int v = blockIdx.x * 64 + lane;
  if (v >= VN) return;
  for (int ob = grp; ob < 128; ob += 4) {  // ob = b*32 + o
    float val = bf1(SRC[(size_t)v * 256 + ob]) + bf1(xn[(size_t)v * 128 + ob]);
    val = fmaxf(val, 0.f);
    out[(size_t)ob * VN + v] = val;
  }
}

// ---------- workspace layout (~184 MB) ----------
static constexpr size_t align_up(size_t x) { return (x + 255) & ~(size_t)255; }
static constexpr size_t OFF_RP    = 0;
static constexpr size_t OFF_FILL  = align_up(OFF_RP + (size_t)(VN + 1) * 4);
static constexpr size_t OFF_CHS   = align_up(OFF_FILL + (size_t)VN * 4);
static constexpr size_t OFF_CHO   = align_up(OFF_CHS + 256);
static constexpr size_t OFF_STATS = align_up(OFF_CHO + 256);
static constexpr size_t OFF_WP    = align_up(OFF_STATS + 1024);     // 32768 shorts = 64 KB
static constexpr size_t OFF_CS    = align_up(OFF_WP + 32768 * 2);
static constexpr size_t OFF_VS    = align_up(OFF_CS + (size_t)EN * 4);
static constexpr size_t OFF_XN    = align_up(OFF_VS + (size_t)EN * 4);
static constexpr size_t OFF_XL    = align_up(OFF_XN + (size_t)VN * 128 * 2);
static constexpr size_t OFF_A     = align_up(OFF_XL + (size_t)VN * 256 * 2);
static constexpr size_t OFF_B     = align_up(OFF_A + (size_t)VN * 256 * 2);
static constexpr size_t OFF_END   = OFF_B + (size_t)VN * 256 * 2;

extern "C" void kernel_launch(void* const* d_in, const int* in_sizes, int n_in,
                              void* d_out, int out_size, void* d_ws, size_t ws_size,
                              hipStream_t stream) {
  if (ws_size < OFF_END) return;  // diagnostic guard (see R1 post-mortem)

  const float* x       = (const float*)d_in[0];
  const int*   rows    = (const int*)d_in[1];
  const int*   cols    = rows + EN;
  const float* lap     = (const float*)d_in[2];
  const float* in_bn_g = (const float*)d_in[3];
  const float* in_bn_b = (const float*)d_in[4];
  const float* in_w    = (const float*)d_in[5];
  const float* in_b    = (const float*)d_in[6];
  const float* h0_bn_g = (const float*)d_in[7];
  const float* h0_bn_b = (const float*)d_in[8];
  const float* h0_w    = (const float*)d_in[9];
  const float* h0_b    = (const float*)d_in[10];
  const float* h1_bn_g = (const float*)d_in[11];
  const float* h1_bn_b = (const float*)d_in[12];
  const float* h1_w    = (const float*)d_in[13];
  const float* h1_b    = (const float*)d_in[14];
  float* outp = (float*)d_out;

  char* ws = (char*)d_ws;
  int*   rp     = (int*)(ws + OFF_RP);
  int*   fill   = (int*)(ws + OFF_FILL);
  int*   chS    = (int*)(ws + OFF_CHS);
  int*   chO    = (int*)(ws + OFF_CHO);
  float* stats  = (float*)(ws + OFF_STATS);
  unsigned short* wbIn = (unsigned short*)(ws + OFF_WP);      // 8192 shorts
  unsigned short* wbH0 = wbIn + 8192;                         // 16384 shorts
  unsigned short* wbH1 = wbH0 + 16384;                        // 8192 shorts
  int*   cs     = (int*)(ws + OFF_CS);
  float* vs     = (float*)(ws + OFF_VS);
  unsigned short* xn = (unsigned short*)(ws + OFF_XN);
  unsigned short* XL = (unsigned short*)(ws + OFF_XL);
  unsigned short* A  = (unsigned short*)(ws + OFF_A);
  unsigned short* B  = (unsigned short*)(ws + OFF_B);

  const int nChunks = (VN + 2047) / 2048;  // 49

  // ---- W pre-pack into MFMA B-fragment order ----
  pack_wb_kernel<<<32, 256, 0, stream>>>(in_w, wbIn, 32, 64);
  pack_wb_kernel<<<64, 256, 0, stream>>>(h0_w, wbH0, 64, 64);
  pack_wb_kernel<<<32, 256, 0, stream>>>(h1_w, wbH1, 64, 32);

  // ---- input BN stats + normalize/transpose ----
  hipMemsetAsync(stats, 0, 1024, stream);
  stats_x_kernel<<<1024, 256, 0, stream>>>(x, stats);
  finalize_stats_kernel<<<1, 64, 0, stream>>>(stats, in_bn_g, in_bn_b, 32);
  bn_transpose_kernel<<<1563, 128, 0, stream>>>(x, stats, xn);

  // ---- CSR build ----
  hipMemsetAsync(fill, 0, (size_t)VN * 4, stream);
  hist_kernel<<<2048, 256, 0, stream>>>(rows, fill);
  scan1_kernel<<<nChunks, 256, 0, stream>>>(fill, rp, chS);
  scan2_kernel<<<1, 64, 0, stream>>>(chS, chO, rp, nChunks);
  scan3_kernel<<<(VN + 255) / 256, 256, 0, stream>>>(rp, chO, fill);
  fill_kernel<<<2048, 256, 0, stream>>>(rows, cols, lap, fill, cs, vs);

  const int G = VN / 4;  // 25000 blocks

  // ---- layer "in": Cin=32 (x0 = xn, stride 128; 256 B rows, unsplit), Cout=64 ----
  spmm_kernel<false><<<G, 256, 0, stream>>>(rp, cs, vs, xn, 128, nullptr, 0, A, 256, 0);
  spmm_kernel<true ><<<G, 256, 0, stream>>>(rp, cs, vs, A, 256, xn, 128, B, 256, 0);
  fused_cheb_kernel<32, 64, 128><<<G, 256, 0, stream>>>(rp, cs, vs, xn, A, B, wbIn, in_b);
  hipMemsetAsync(stats, 0, 1024, stream);
  stats_out_kernel<<<256, 256, 0, stream>>>(A, stats);
  finalize_stats_kernel<<<1, 64, 0, stream>>>(stats, h0_bn_g, h0_bn_b, 64);
  bn_relu_kernel<<<VN * 64 / 256, 256, 0, stream>>>(A, stats, XL);

  // ---- layer h0: Cin=64, Cout=64; SpMMs split into batch-half slices ----
  spmm_kernel<false><<<G, 256, 0, stream>>>(rp, cs, vs, XL, 256, nullptr, 0, A, 256, 0);
  spmm_kernel<false><<<G, 256, 0, stream>>>(rp, cs, vs, XL, 256, nullptr, 0, A, 256, 128);
  spmm_kernel<true ><<<G, 256, 0, stream>>>(rp, cs, vs, A, 256, XL, 256, B, 256, 0);
  spmm_kernel<true ><<<G, 256, 0, stream>>>(rp, cs, vs, A, 256, XL, 256, B, 256, 128);
  fused_cheb_kernel<64, 64, 256><<<G, 256, 0, stream>>>(rp, cs, vs, XL, A, B, wbH0, h0_b);
  hipMemsetAsync(stats, 0, 1024, stream);
  stats_out_kernel<<<256, 256, 0, stream>>>(A, stats);
  finalize_stats_kernel<<<1, 64, 0, stream>>>(stats, h1_bn_g, h1_bn_b, 64);
  bn_relu_kernel<<<VN * 64 / 256, 256, 0, stream>>>(A, stats, XL);

  // ---- layer h1: Cin=64, Cout=32; SpMMs split into batch-half slices ----
  spmm_kernel<false><<<G, 256, 0, stream>>>(rp, cs, vs, XL, 256, nullptr, 0, A, 256, 0);
  spmm_kernel<false><<<G, 256, 0, stream>>>(rp, cs, vs, XL, 256, nullptr, 0, A, 256, 128);
  spmm_kernel<true ><<<G, 256, 0, stream>>>(rp, cs, vs, A, 256, XL, 256, B, 256, 0);
  spmm_kernel<true ><<<G, 256, 0, stream>>>(rp, cs, vs, A, 256, XL, 256, B, 256, 128);
  fused_cheb_kernel<64, 32, 256><<<G, 256, 0, stream>>>(rp, cs, vs, XL, A, B, wbH1, h1_b);

  // ---- residual + relu + transpose to (B,32,V) ----
  final_kernel<<<1563, 256, 0, stream>>>(A, xn, outp);
}